// Round 5
// baseline (430.384 us; speedup 1.0000x reference)
//
#include <hip/hip_runtime.h>

#define HSZ 32
#define TSEQ 2048
#define NBATCH 256

typedef float v2f __attribute__((ext_vector_type(2)));
typedef unsigned int v2u __attribute__((ext_vector_type(2)));

__device__ __forceinline__ v2f make2(float a, float b) {
    v2f r; r.x = a; r.y = b; return r;
}

__device__ __forceinline__ float hw_exp2(float x) {
#if __has_builtin(__builtin_amdgcn_exp2f)
    return __builtin_amdgcn_exp2f(x);
#else
    return exp2f(x);
#endif
}

__device__ __forceinline__ float hw_rcp(float x) {
#if __has_builtin(__builtin_amdgcn_rcpf)
    return __builtin_amdgcn_rcpf(x);
#else
    return 1.0f / x;
#endif
}

__device__ __forceinline__ float readlane_f(float v, int lane) {
    return __uint_as_float(__builtin_amdgcn_readlane(__float_as_uint(v), lane));
}

// Direction-agnostic cross-half combine: returns v[lane&31] + v[(lane&31)+32]
// in ALL lanes, regardless of which way the swap moves halves. (Proven R2/R3.)
__device__ __forceinline__ float half_sum(float v) {
#if __has_builtin(__builtin_amdgcn_permlane32_swap)
    v2u r = __builtin_amdgcn_permlane32_swap(__float_as_uint(v), __float_as_uint(v), false, false);
    return __uint_as_float(r.x) + __uint_as_float(r.y);
#else
    return v + __shfl_xor(v, 32, 64);
#endif
}

#if __has_builtin(__builtin_elementwise_fma)
#define PKFMA(a, b, cc) __builtin_elementwise_fma((a), (b), (cc))
#else
__device__ __forceinline__ v2f PKFMA(v2f a, v2f b, v2f c) {
    return make2(fmaf(a.x, b.x, c.x), fmaf(a.y, b.y, c.y));
}
#endif

#define NL2E -1.44269504088896340736f   // -log2(e)

__global__ __launch_bounds__(64, 1) void lstm_last_kernel(
    const float* __restrict__ x,      // [B, T, 1]
    const float* __restrict__ W_ih,   // [4H, 1]
    const float* __restrict__ W_hh,   // [4H, H]
    const float* __restrict__ b_ih,   // [4H]
    const float* __restrict__ b_hh,   // [4H]
    float* __restrict__ out)          // [B, H]
{
    const int b    = blockIdx.x;
    const int l    = threadIdx.x;   // 0..63
    const int k    = l & 31;        // hidden unit index
    const int half = l >> 5;        // 0: rows (i_k, g_k); 1: rows (f_k, o_k)
    const int row0 = l;             // i_k (half0) or f_k (half1)
    const int row1 = l + 64;        // g_k (half0) or o_k (half1)

    __shared__ float x_lds[TSEQ + 4];

    // ---- one-time staging: x row into LDS (float4, coalesced) ----
    const float4* xrow4 = (const float4*)(x + (size_t)b * TSEQ);
    float4* xl4 = (float4*)x_lds;
    #pragma unroll
    for (int j = 0; j < (TSEQ / 4) / 64; ++j)   // 8 iters
        xl4[j * 64 + l] = xrow4[j * 64 + l];
    if (l == 0) x_lds[TSEQ] = 0.0f;

    // ---- one-time: weights packed along the GATE axis, pre-scaled so every
    //      sigmoid is bare rcp(1+exp2(d)).
    //      .x lane: dot0 (i/f), scale -log2e
    //      .y lane: dot1 (g: tanh -> scale -2log2e; o: sigmoid -> -log2e)
    const float sc0 = NL2E;
    const float sc1 = half ? NL2E : 2.0f * NL2E;

    v2f wp[HSZ];   // wp[j] = (W[row0,j]*sc0, W[row1,j]*sc1)
    #pragma unroll
    for (int j = 0; j < HSZ; j += 4) {
        float4 a  = *(const float4*)(W_hh + row0 * HSZ + j);
        float4 c4 = *(const float4*)(W_hh + row1 * HSZ + j);
        wp[j]   = make2(a.x * sc0, c4.x * sc1);
        wp[j+1] = make2(a.y * sc0, c4.y * sc1);
        wp[j+2] = make2(a.z * sc0, c4.z * sc1);
        wp[j+3] = make2(a.w * sc0, c4.w * sc1);
    }
    const v2f wxp   = make2(W_ih[row0] * sc0, W_ih[row1] * sc1);
    const v2f biasp = make2((b_ih[row0] + b_hh[row0]) * sc0,
                            (b_ih[row1] + b_hh[row1]) * sc1);

    const float s1mul = half ? 1.0f : 2.0f;    // loop-invariant (hoisted cndmask)
    const float s1add = half ? 0.0f : -1.0f;

    float c  = 0.0f;   // cell state
    float hk = 0.0f;   // h_k valid in lanes 32..63

    __syncthreads();
    float xt = x_lds[0];

    #pragma unroll 1
    for (int t = 0; t < TSEQ; ++t) {
        // ---- broadcast h (lanes 32..63) into 32 wave-uniform scalars ----
        float hs[HSZ];
        #pragma unroll
        for (int j = 0; j < HSZ; ++j) hs[j] = readlane_f(hk, 32 + j);

        float xt_next = x_lds[t + 1];   // prefetch, latency hidden under dots

        // ---- both dots at once: acc pair = (d0, d1); h enters as a SPLAT
        //      (same 32-bit value both halves -> op_sel, no pair formation) ----
        v2f q0 = PKFMA(wxp, make2(xt, xt), biasp);
        v2f q1 = make2(0.f, 0.f), q2 = make2(0.f, 0.f), q3 = make2(0.f, 0.f);
        #pragma unroll
        for (int j = 0; j < HSZ; j += 4) {
            q0 = PKFMA(wp[j],   make2(hs[j],   hs[j]),   q0);
            q1 = PKFMA(wp[j+1], make2(hs[j+1], hs[j+1]), q1);
            q2 = PKFMA(wp[j+2], make2(hs[j+2], hs[j+2]), q2);
            q3 = PKFMA(wp[j+3], make2(hs[j+3], hs[j+3]), q3);
        }
        v2f r = (q0 + q1) + (q2 + q3);   // r.x = d0, r.y = d1 (no horizontal add!)

        float a0 = hw_rcp(1.0f + hw_exp2(r.x));                    // sigmoid(i/f)
        float a1 = fmaf(s1mul, hw_rcp(1.0f + hw_exp2(r.y)), s1add); // tanh(g)/sigm(o)

        // half0 contributes i*g, half1 contributes f*c; cross-half SUM = c_new
        float v  = a0 * (half ? c : a1);
        float cn = half_sum(v);
        c = cn;

        float th = fmaf(2.0f, hw_rcp(1.0f + hw_exp2(cn * (2.0f * NL2E))), -1.0f); // tanh(c)
        hk = a1 * th;   // valid (o * tanh(c)) in lanes 32..63

        xt = xt_next;
    }

    if (half) out[b * HSZ + k] = hk;
}

extern "C" void kernel_launch(void* const* d_in, const int* in_sizes, int n_in,
                              void* d_out, int out_size, void* d_ws, size_t ws_size,
                              hipStream_t stream) {
    const float* x    = (const float*)d_in[0];
    const float* W_ih = (const float*)d_in[1];
    const float* W_hh = (const float*)d_in[2];
    const float* b_ih = (const float*)d_in[3];
    const float* b_hh = (const float*)d_in[4];
    float* out = (float*)d_out;

    lstm_last_kernel<<<NBATCH, 64, 0, stream>>>(x, W_ih, W_hh, b_ih, b_hh, out);
}